// Round 1
// baseline (216.967 us; speedup 1.0000x reference)
//
#include <hip/hip_runtime.h>
#include <math.h>

// Mamba2 chunked SSD forward (inclusive segsum variant), fp32.
// Shapes hardcoded per setup_inputs(): b=2, s=4096, h=16, p=64, n=64, BL=64.
//
// Pipeline:
//   k1: per-(b,c,h) chunk cumsum of A + decayed local state (p x n) -> ws
//   k2: inter-chunk scan  carry[z] = exp(total[z-1])*(carry[z-1]+local[z-1]),
//       in-place over the states buffer (states[z] becomes the ENTERING state)
//   k3: per-(b,c,h)  Y = ((C B^T) o L) X  +  exp(cs) o (C carry^T)

#define NB 2
#define SQ 4096
#define NH 16
#define NP 64
#define NN 64
#define NC 64   // chunks = SQ/64

// ---------------------------------------------------------------- kernel 1
__global__ __launch_bounds__(256) void k1_state(
    const float* __restrict__ X, const float* __restrict__ A,
    const float* __restrict__ Bm, float* __restrict__ states,
    float* __restrict__ csw) {
  const int bid = blockIdx.x;
  const int h = bid & 15;
  const int c = (bid >> 4) & 63;
  const int b = bid >> 10;

  __shared__ __align__(16) float Xs[64][64];
  __shared__ __align__(16) float Bs[64][64];
  __shared__ float dss[64];

  const int tid = threadIdx.x;

  // wave 0: load A chunk, inclusive wave-scan cumsum, store cs + decay d[l]
  if (tid < 64) {
    float v = A[(size_t)((b * SQ + c * 64 + tid) * NH) + h];
#pragma unroll
    for (int off = 1; off < 64; off <<= 1) {
      float u = __shfl_up(v, off, 64);
      if (tid >= off) v += u;
    }
    csw[(size_t)((b * NH + h) * NC + c) * 64 + tid] = v;
    float total = __shfl(v, 63, 64);
    dss[tid] = __expf(total - v);  // exp(cs[63]-cs[l]) <= 1
  }

  // stage X,B chunk rows into LDS (row-major [l][col]), coalesced
  const float* xg = X + (size_t)(b * SQ + c * 64) * 1024 + h * 64;
  const float* bg = Bm + (size_t)(b * SQ + c * 64) * 1024 + h * 64;
  const int r = tid >> 6, q = tid & 63;
#pragma unroll
  for (int rr = r; rr < 64; rr += 4) {
    Xs[rr][q] = xg[(size_t)rr * 1024 + q];
    Bs[rr][q] = bg[(size_t)rr * 1024 + q];
  }
  __syncthreads();

  // scale B rows by decay
#pragma unroll
  for (int e = tid; e < 4096; e += 256) Bs[e >> 6][e & 63] *= dss[e >> 6];
  __syncthreads();

  // states[p][n] = sum_l Xs[l][p] * Bs_scaled[l][n]   (k = l over rows: no conflicts)
  const int tc = tid & 15, tr = tid >> 4;  // p = tr*4+i, n = tc*4+j
  float acc[4][4] = {};
  for (int l = 0; l < 64; ++l) {
    float4 xv = *(const float4*)&Xs[l][tr * 4];
    float4 bv = *(const float4*)&Bs[l][tc * 4];
    float xa[4] = {xv.x, xv.y, xv.z, xv.w};
    float ba[4] = {bv.x, bv.y, bv.z, bv.w};
#pragma unroll
    for (int i = 0; i < 4; ++i)
#pragma unroll
      for (int j = 0; j < 4; ++j) acc[i][j] = fmaf(xa[i], ba[j], acc[i][j]);
  }

  float* sg = states + (size_t)bid * 4096;  // layout ((b*NC+c)*NH+h)*p*n == bid*4096
#pragma unroll
  for (int i = 0; i < 4; ++i) {
    float4 v = make_float4(acc[i][0], acc[i][1], acc[i][2], acc[i][3]);
    *(float4*)&sg[(tr * 4 + i) * 64 + tc * 4] = v;
  }
}

// ---------------------------------------------------------------- kernel 2
// one thread owns one (p,n) element of one (b,h); in-place scan over chunks
__global__ __launch_bounds__(256) void k2_scan(
    float* __restrict__ states, const float* __restrict__ csw) {
  const int tid = threadIdx.x;
  const int sl = blockIdx.x & 15;
  const int h = (blockIdx.x >> 4) & 15;
  const int b = blockIdx.x >> 8;
  const int e = sl * 256 + tid;

  const float* totals = csw + (size_t)((b * NH + h) * NC) * 64;
  float carry = 0.f;
  for (int z = 0; z < NC; ++z) {
    float total = totals[z * 64 + 63];  // chunk-z cumsum total (broadcast)
    size_t idx = (size_t)((b * NC + z) * NH + h) * 4096 + e;
    float tmp = states[idx];
    states[idx] = carry;                      // entering state of chunk z
    carry = __expf(total) * (carry + tmp);    // inclusive-segsum recurrence
  }
}

// ---------------------------------------------------------------- kernel 3
__global__ __launch_bounds__(256) void k3_y(
    const float* __restrict__ X, const float* __restrict__ Bm,
    const float* __restrict__ Cm, const float* __restrict__ states,
    const float* __restrict__ csw, float* __restrict__ Y) {
  const int bid = blockIdx.x;
  const int h = bid & 15;
  const int c = (bid >> 4) & 63;
  const int b = bid >> 10;

  __shared__ __align__(16) float Ct[64][68];   // C transposed: [n][l], pad 68
  __shared__ __align__(16) float Bt[64][68];   // B transposed: [n][s]; reused as carry^T [n][p]
  __shared__ __align__(16) float Xs[64][64];   // X row-major: [s][p]
  __shared__ __align__(16) float SLt[64][68];  // (S o L)^T: [s][l]
  __shared__ float css[64];

  const int tid = threadIdx.x;
  const float* crow = csw + (size_t)((b * NH + h) * NC + c) * 64;
  if (tid < 64) css[tid] = crow[tid];

  const float* xg = X + (size_t)(b * SQ + c * 64) * 1024 + h * 64;
  const float* bg = Bm + (size_t)(b * SQ + c * 64) * 1024 + h * 64;
  const float* cg = Cm + (size_t)(b * SQ + c * 64) * 1024 + h * 64;
  const int r = tid >> 6, q = tid & 63;
#pragma unroll
  for (int rr = r; rr < 64; rr += 4) {
    Xs[rr][q] = xg[(size_t)rr * 1024 + q];
    Bt[q][rr] = bg[(size_t)rr * 1024 + q];  // transpose write (pad 68: 8-way max)
    Ct[q][rr] = cg[(size_t)rr * 1024 + q];
  }
  __syncthreads();

  const int tc = tid & 15, tr = tid >> 4;

  // Phase A: S[l][s] = sum_n C[l][n]*B[s][n];  SLt[s][l] = S*L
  {
    float acc[4][4] = {};
    for (int n = 0; n < 64; ++n) {
      float4 cv = *(const float4*)&Ct[n][tr * 4];
      float4 bv = *(const float4*)&Bt[n][tc * 4];
      float ca[4] = {cv.x, cv.y, cv.z, cv.w};
      float ba[4] = {bv.x, bv.y, bv.z, bv.w};
#pragma unroll
      for (int i = 0; i < 4; ++i)
#pragma unroll
        for (int j = 0; j < 4; ++j) acc[i][j] = fmaf(ca[i], ba[j], acc[i][j]);
    }
#pragma unroll
    for (int j = 0; j < 4; ++j) {
      const int s = tc * 4 + j;
      const float cse = (s == 0) ? 0.f : css[s - 1];  // exclusive cumsum
      float o[4];
#pragma unroll
      for (int i = 0; i < 4; ++i) {
        const int l = tr * 4 + i;
        // L[l][s] = exp(cs[l] - cs[s] + A[s]) = exp(cs[l] - cse[s]) for l>=s
        o[i] = (l >= s) ? acc[i][j] * __expf(css[l] - cse) : 0.f;
      }
      *(float4*)&SLt[s][tr * 4] = make_float4(o[0], o[1], o[2], o[3]);
    }
  }
  __syncthreads();

  // reuse Bt as carry^T [n][p]  (carry stored (p,n) in ws)
  const float* stg = states + (size_t)bid * 4096;
#pragma unroll
  for (int rr = r; rr < 64; rr += 4) Bt[q][rr] = stg[rr * 64 + q];
  __syncthreads();

  // Phase B: Y_diag[l][p] = sum_s SLt[s][l] * Xs[s][p]
  float accd[4][4] = {};
  for (int s = 0; s < 64; ++s) {
    float4 lv = *(const float4*)&SLt[s][tr * 4];
    float4 xv = *(const float4*)&Xs[s][tc * 4];
    float la[4] = {lv.x, lv.y, lv.z, lv.w};
    float xa[4] = {xv.x, xv.y, xv.z, xv.w};
#pragma unroll
    for (int i = 0; i < 4; ++i)
#pragma unroll
      for (int j = 0; j < 4; ++j) accd[i][j] = fmaf(la[i], xa[j], accd[i][j]);
  }

  // Phase C: Y_off[l][p] = sum_n Ct[n][l] * carryT[n][p]
  float acco[4][4] = {};
  for (int n = 0; n < 64; ++n) {
    float4 cv = *(const float4*)&Ct[n][tr * 4];
    float4 gv = *(const float4*)&Bt[n][tc * 4];
    float ca[4] = {cv.x, cv.y, cv.z, cv.w};
    float ga[4] = {gv.x, gv.y, gv.z, gv.w};
#pragma unroll
    for (int i = 0; i < 4; ++i)
#pragma unroll
      for (int j = 0; j < 4; ++j) acco[i][j] = fmaf(ca[i], ga[j], acco[i][j]);
  }

  // Y = Y_diag + exp(cs[l]) * Y_off
  float* yg = Y + (size_t)(b * SQ + c * 64) * 1024 + h * 64;
#pragma unroll
  for (int i = 0; i < 4; ++i) {
    const int l = tr * 4 + i;
    const float sc = __expf(css[l]);
    float4 v = make_float4(accd[i][0] + sc * acco[i][0],
                           accd[i][1] + sc * acco[i][1],
                           accd[i][2] + sc * acco[i][2],
                           accd[i][3] + sc * acco[i][3]);
    *(float4*)&yg[(size_t)l * 1024 + tc * 4] = v;
  }
}

// ---------------------------------------------------------------- launch
extern "C" void kernel_launch(void* const* d_in, const int* in_sizes, int n_in,
                              void* d_out, int out_size, void* d_ws, size_t ws_size,
                              hipStream_t stream) {
  (void)in_sizes; (void)n_in; (void)out_size; (void)ws_size;
  const float* X  = (const float*)d_in[0];
  const float* A  = (const float*)d_in[1];
  const float* Bm = (const float*)d_in[2];
  const float* Cm = (const float*)d_in[3];
  float* Y = (float*)d_out;

  // workspace: states (b*c*h*p*n = 8388608 f32) + cumsum (b*h*c*64 = 131072 f32)
  float* states = (float*)d_ws;
  float* csw    = states + (size_t)NB * NC * NH * NP * NN;

  k1_state<<<NB * NC * NH, 256, 0, stream>>>(X, A, Bm, states, csw);
  k2_scan<<<NB * NH * 16, 256, 0, stream>>>(states, csw);
  k3_y<<<NB * NC * NH, 256, 0, stream>>>(X, Bm, Cm, states, csw, Y);
}

// Round 3
// 177.750 us; speedup vs baseline: 1.2206x; 1.2206x over previous
//
#include <hip/hip_runtime.h>
#include <math.h>

// Mamba2 chunked SSD forward (inclusive segsum), fp32 in/out, split-f16 MFMA.
// b=2, s=4096, h=16, p=n=64, BL=64, chunks NC=64.
//
// k1: per-(b,c,h): cumsum(A) -> csw; local state (p x n) = X^T * (decay o B) via MFMA
// k2: inter-chunk scan: carry[z] = exp(total[z-1])*(carry[z-1]+local[z-1]) (in-place)
// k3: per-(b,c,h): Y = ((C B^T) o L) X + exp(cs) o (C carry^T) via MFMA
//
// Split-f16: x = hi + lo (f16 each); products hi*hi + hi*lo + lo*hi in fp32 acc.
// MFMA = v_mfma_f32_16x16x16_f16 (classic layout):
//   A: row=lane&15, k=4*(lane>>4)+i ; B: col=lane&15, same k ; D: row=4*(lane>>4)+r, col=lane&15
// LDS tiles: [64 rows][128B], XOR-swizzle byte^=((row&7)<<4) on both write & read.

#define NB 2
#define SQ 4096
#define NH 16
#define NC 64

typedef _Float16 h4 __attribute__((ext_vector_type(4)));
typedef float f4 __attribute__((ext_vector_type(4)));

#define MFMA(a, b, c) __builtin_amdgcn_mfma_f32_16x16x16f16((a), (b), (c), 0, 0, 0)

__device__ __forceinline__ int swzb(int row, int byte_in_row) {
  return (row << 7) + (byte_in_row ^ ((row & 7) << 4));
}
__device__ __forceinline__ h4 ldh4(const _Float16* buf, int row, int chunk8) {
  return *reinterpret_cast<const h4*>(reinterpret_cast<const char*>(buf) +
                                      swzb(row, chunk8 << 3));
}
__device__ __forceinline__ void sth4(_Float16* buf, int row, int chunk8, h4 v) {
  *reinterpret_cast<h4*>(reinterpret_cast<char*>(buf) + swzb(row, chunk8 << 3)) = v;
}
__device__ __forceinline__ void sth1(_Float16* buf, int row, int col, _Float16 v) {
  *reinterpret_cast<_Float16*>(reinterpret_cast<char*>(buf) + swzb(row, col << 1)) = v;
}
// float4 -> hi/lo h4
__device__ __forceinline__ void cvt4(float x, float y, float z, float w, h4& hi, h4& lo) {
  hi.x = (_Float16)x; lo.x = (_Float16)(x - (float)hi.x);
  hi.y = (_Float16)y; lo.y = (_Float16)(y - (float)hi.y);
  hi.z = (_Float16)z; lo.z = (_Float16)(z - (float)hi.z);
  hi.w = (_Float16)w; lo.w = (_Float16)(w - (float)hi.w);
}

// ---------------------------------------------------------------- kernel 1
__global__ __launch_bounds__(256) void k1_state(
    const float* __restrict__ X, const float* __restrict__ A,
    const float* __restrict__ Bm, float* __restrict__ states,
    float* __restrict__ csw) {
  const int bid = blockIdx.x;
  const int h = bid & 15;
  const int c = (bid >> 4) & 63;
  const int b = bid >> 10;
  const int tid = threadIdx.x;

  __shared__ __align__(16) _Float16 Xthi[4096], Xtlo[4096];  // X^T: [p][l]
  __shared__ __align__(16) _Float16 Bthi[4096], Btlo[4096];  // (d o B)^T: [n][l]
  __shared__ float dss[64];

  if (tid < 64) {
    float v = A[(size_t)((b * SQ + c * 64 + tid) * NH) + h];
#pragma unroll
    for (int off = 1; off < 64; off <<= 1) {
      float u = __shfl_up(v, off, 64);
      if (tid >= off) v += u;
    }
    csw[(size_t)((b * NH + h) * NC + c) * 64 + tid] = v;
    float total = __shfl(v, 63, 64);
    dss[tid] = __expf(total - v);
  }
  __syncthreads();

  // transpose-stage X and decayed B (rows l -> cols)
  const int l = tid & 63, cb = tid >> 6;
  const float* xs = X + (size_t)(b * SQ + c * 64 + l) * 1024 + h * 64 + cb * 16;
  const float* bs = Bm + (size_t)(b * SQ + c * 64 + l) * 1024 + h * 64 + cb * 16;
  const float ds = dss[l];
#pragma unroll
  for (int i = 0; i < 4; ++i) {
    float4 xv = ((const float4*)xs)[i];
    float4 bv = ((const float4*)bs)[i];
    h4 hx, lx, hb, lb;
    cvt4(xv.x, xv.y, xv.z, xv.w, hx, lx);
    cvt4(bv.x * ds, bv.y * ds, bv.z * ds, bv.w * ds, hb, lb);
    const int pr = cb * 16 + 4 * i;
    sth1(Xthi, pr + 0, l, hx.x); sth1(Xtlo, pr + 0, l, lx.x);
    sth1(Xthi, pr + 1, l, hx.y); sth1(Xtlo, pr + 1, l, lx.y);
    sth1(Xthi, pr + 2, l, hx.z); sth1(Xtlo, pr + 2, l, lx.z);
    sth1(Xthi, pr + 3, l, hx.w); sth1(Xtlo, pr + 3, l, lx.w);
    sth1(Bthi, pr + 0, l, hb.x); sth1(Btlo, pr + 0, l, lb.x);
    sth1(Bthi, pr + 1, l, hb.y); sth1(Btlo, pr + 1, l, lb.y);
    sth1(Bthi, pr + 2, l, hb.z); sth1(Btlo, pr + 2, l, lb.z);
    sth1(Bthi, pr + 3, l, hb.w); sth1(Btlo, pr + 3, l, lb.w);
  }
  __syncthreads();

  // states[p][n] = sum_l Xt[p][l] * Bt[n][l]
  const int w = tid >> 6, li = tid & 15, g = (tid & 63) >> 4;
  f4 acc[4] = {};
#pragma unroll
  for (int ks = 0; ks < 4; ++ks) {
    const int ca = 4 * ks + g;
    h4 ahi = ldh4(Xthi, 16 * w + li, ca);
    h4 alo = ldh4(Xtlo, 16 * w + li, ca);
#pragma unroll
    for (int ct = 0; ct < 4; ++ct) {
      h4 bhi = ldh4(Bthi, 16 * ct + li, ca);
      h4 blo = ldh4(Btlo, 16 * ct + li, ca);
      acc[ct] = MFMA(ahi, bhi, acc[ct]);
      acc[ct] = MFMA(ahi, blo, acc[ct]);
      acc[ct] = MFMA(alo, bhi, acc[ct]);
    }
  }
  float* sg = states + (size_t)bid * 4096;
#pragma unroll
  for (int r = 0; r < 4; ++r) {
    const int p = 16 * w + 4 * g + r;
#pragma unroll
    for (int ct = 0; ct < 4; ++ct) sg[p * 64 + 16 * ct + li] = acc[ct][r];
  }
}

// ---------------------------------------------------------------- kernel 2
__global__ __launch_bounds__(256) void k2_scan(
    float* __restrict__ states, const float* __restrict__ csw) {
  const int tid = threadIdx.x;
  const int sl = blockIdx.x & 15;
  const int h = (blockIdx.x >> 4) & 15;
  const int b = blockIdx.x >> 8;

  __shared__ float et[64];
  if (tid < 64)
    et[tid] = __expf(csw[((size_t)(b * NH + h) * NC + tid) * 64 + 63]);
  __syncthreads();

  const int e = sl * 256 + tid;
  const size_t base = ((size_t)b * NC * NH + h) * 4096 + e;
  const size_t zs = (size_t)NH * 4096;

  float carry = 0.f;
  float pre[4];
#pragma unroll
  for (int j = 0; j < 4; ++j) pre[j] = states[base + j * zs];
  for (int zb = 0; zb < 16; ++zb) {
    float cur[4];
#pragma unroll
    for (int j = 0; j < 4; ++j) cur[j] = pre[j];
    if (zb < 15) {
#pragma unroll
      for (int j = 0; j < 4; ++j) pre[j] = states[base + (size_t)(4 * zb + 4 + j) * zs];
    }
#pragma unroll
    for (int j = 0; j < 4; ++j) {
      const int z = 4 * zb + j;
      states[base + (size_t)z * zs] = carry;
      carry = et[z] * (carry + cur[j]);
    }
  }
}

// ---------------------------------------------------------------- kernel 3
__global__ __launch_bounds__(256) void k3_y(
    const float* __restrict__ X, const float* __restrict__ Bm,
    const float* __restrict__ Cm, const float* __restrict__ states,
    const float* __restrict__ csw, float* __restrict__ Y) {
  const int bid = blockIdx.x;
  const int h = bid & 15;
  const int c = (bid >> 4) & 63;
  const int b = bid >> 10;
  const int tid = threadIdx.x;

  __shared__ __align__(16) _Float16 Chi[4096], Clo[4096];  // C: [l][n]
  __shared__ __align__(16) _Float16 Shi[4096], Slo[4096];  // B: [s][n] -> SL: [l][s]
  __shared__ __align__(16) _Float16 Vhi[4096], Vlo[4096];  // X^T: [p][s] -> carry: [p][n]
  __shared__ float css[64];

  if (tid < 64)
    css[tid] = csw[((size_t)(b * NH + h) * NC + c) * 64 + tid];

  // prefetch carry (entering state) into registers; consumed at phase C staging
  const float* stg = states + (size_t)bid * 4096;
  const int r0 = tid >> 2, q0 = tid & 3;
  float4 cr[4];
#pragma unroll
  for (int i = 0; i < 4; ++i)
    cr[i] = ((const float4*)(stg + r0 * 64 + q0 * 16))[i];

  // direct staging: C and B (row-major rows r0)
  {
    const float* cgp = Cm + (size_t)(b * SQ + c * 64 + r0) * 1024 + h * 64 + q0 * 16;
    const float* bgp = Bm + (size_t)(b * SQ + c * 64 + r0) * 1024 + h * 64 + q0 * 16;
#pragma unroll
    for (int i = 0; i < 4; ++i) {
      float4 cv = ((const float4*)cgp)[i];
      float4 bv = ((const float4*)bgp)[i];
      h4 hc, lc, hb, lb;
      cvt4(cv.x, cv.y, cv.z, cv.w, hc, lc);
      cvt4(bv.x, bv.y, bv.z, bv.w, hb, lb);
      sth4(Chi, r0, q0 * 4 + i, hc); sth4(Clo, r0, q0 * 4 + i, lc);
      sth4(Shi, r0, q0 * 4 + i, hb); sth4(Slo, r0, q0 * 4 + i, lb);
    }
  }
  // transpose staging: X -> Vhi/Vlo [p][s]
  {
    const int l = tid & 63, pb = tid >> 6;
    const float* xs = X + (size_t)(b * SQ + c * 64 + l) * 1024 + h * 64 + pb * 16;
#pragma unroll
    for (int i = 0; i < 4; ++i) {
      float4 xv = ((const float4*)xs)[i];
      h4 hx, lx;
      cvt4(xv.x, xv.y, xv.z, xv.w, hx, lx);
      const int pr = pb * 16 + 4 * i;
      sth1(Vhi, pr + 0, l, hx.x); sth1(Vlo, pr + 0, l, lx.x);
      sth1(Vhi, pr + 1, l, hx.y); sth1(Vlo, pr + 1, l, lx.y);
      sth1(Vhi, pr + 2, l, hx.z); sth1(Vlo, pr + 2, l, lx.z);
      sth1(Vhi, pr + 3, l, hx.w); sth1(Vlo, pr + 3, l, lx.w);
    }
  }
  __syncthreads();

  const int w = tid >> 6, li = tid & 15, g = (tid & 63) >> 4;

  // phase A: S[l][s] = sum_n C[l][n] * B[s][n]
  f4 accS[4] = {};
#pragma unroll
  for (int ks = 0; ks < 4; ++ks) {
    const int ca = 4 * ks + g;
    h4 ahi = ldh4(Chi, 16 * w + li, ca);
    h4 alo = ldh4(Clo, 16 * w + li, ca);
#pragma unroll
    for (int ct = 0; ct < 4; ++ct) {
      h4 bhi = ldh4(Shi, 16 * ct + li, ca);
      h4 blo = ldh4(Slo, 16 * ct + li, ca);
      accS[ct] = MFMA(ahi, bhi, accS[ct]);
      accS[ct] = MFMA(ahi, blo, accS[ct]);
      accS[ct] = MFMA(alo, bhi, accS[ct]);
    }
  }
  __syncthreads();  // B-data reads done; Shi/Slo now become SL

  // SL[l][s] = (l>=s) ? S * exp(cs[l] - cs_excl[s]) : 0
#pragma unroll
  for (int ct = 0; ct < 4; ++ct) {
    const int s = 16 * ct + li;
    const float cse = (s == 0) ? 0.f : css[s - 1];
#pragma unroll
    for (int r = 0; r < 4; ++r) {
      const int lrow = 16 * w + 4 * g + r;
      float slv = (lrow >= s) ? accS[ct][r] * __expf(css[lrow] - cse) : 0.f;
      _Float16 hv = (_Float16)slv;
      _Float16 lv = (_Float16)(slv - (float)hv);
      sth1(Shi, lrow, s, hv);
      sth1(Slo, lrow, s, lv);
    }
  }
  __syncthreads();

  // phase B: Yd[l][p] = sum_s SL[l][s] * Xt[p][s]
  f4 accB[4] = {};
#pragma unroll
  for (int ks = 0; ks < 4; ++ks) {
    const int ca = 4 * ks + g;
    h4 ahi = ldh4(Shi, 16 * w + li, ca);
    h4 alo = ldh4(Slo, 16 * w + li, ca);
#pragma unroll
    for (int ct = 0; ct < 4; ++ct) {
      h4 bhi = ldh4(Vhi, 16 * ct + li, ca);
      h4 blo = ldh4(Vlo, 16 * ct + li, ca);
      accB[ct] = MFMA(ahi, bhi, accB[ct]);
      accB[ct] = MFMA(ahi, blo, accB[ct]);
      accB[ct] = MFMA(alo, bhi, accB[ct]);
    }
  }
  __syncthreads();  // X reads done; Vhi/Vlo now become carry [p][n]

  {
    h4 hg, lg;
#pragma unroll
    for (int i = 0; i < 4; ++i) {
      cvt4(cr[i].x, cr[i].y, cr[i].z, cr[i].w, hg, lg);
      sth4(Vhi, r0, q0 * 4 + i, hg);
      sth4(Vlo, r0, q0 * 4 + i, lg);
    }
  }
  __syncthreads();

  // phase C: Yo[l][p] = sum_n C[l][n] * carry[p][n]
  f4 accC[4] = {};
#pragma unroll
  for (int ks = 0; ks < 4; ++ks) {
    const int ca = 4 * ks + g;
    h4 ahi = ldh4(Chi, 16 * w + li, ca);
    h4 alo = ldh4(Clo, 16 * w + li, ca);
#pragma unroll
    for (int ct = 0; ct < 4; ++ct) {
      h4 bhi = ldh4(Vhi, 16 * ct + li, ca);
      h4 blo = ldh4(Vlo, 16 * ct + li, ca);
      accC[ct] = MFMA(ahi, bhi, accC[ct]);
      accC[ct] = MFMA(ahi, blo, accC[ct]);
      accC[ct] = MFMA(alo, bhi, accC[ct]);
    }
  }

  // Y = Yd + exp(cs[l]) * Yo
  float* yg = Y + (size_t)(b * SQ + c * 64) * 1024 + h * 64;
#pragma unroll
  for (int r = 0; r < 4; ++r) {
    const int lrow = 16 * w + 4 * g + r;
    const float el = __expf(css[lrow]);
#pragma unroll
    for (int ct = 0; ct < 4; ++ct)
      yg[(size_t)lrow * 1024 + 16 * ct + li] = accB[ct][r] + el * accC[ct][r];
  }
}

// ---------------------------------------------------------------- launch
extern "C" void kernel_launch(void* const* d_in, const int* in_sizes, int n_in,
                              void* d_out, int out_size, void* d_ws, size_t ws_size,
                              hipStream_t stream) {
  (void)in_sizes; (void)n_in; (void)out_size; (void)ws_size;
  const float* X  = (const float*)d_in[0];
  const float* A  = (const float*)d_in[1];
  const float* Bm = (const float*)d_in[2];
  const float* Cm = (const float*)d_in[3];
  float* Y = (float*)d_out;

  float* states = (float*)d_ws;                             // 8388608 f32
  float* csw    = states + (size_t)NB * NC * NH * 64 * 64;  // 131072 f32

  k1_state<<<NB * NC * NH, 256, 0, stream>>>(X, A, Bm, states, csw);
  k2_scan<<<NB * NH * 16, 256, 0, stream>>>(states, csw);
  k3_y<<<NB * NC * NH, 256, 0, stream>>>(X, Bm, Cm, states, csw, Y);
}

// Round 4
// 175.085 us; speedup vs baseline: 1.2392x; 1.0152x over previous
//
#include <hip/hip_runtime.h>
#include <math.h>

// Mamba2 chunked SSD forward (inclusive segsum), fp32 in/out, mixed split-f16 MFMA.
// b=2, s=4096, h=16, p=n=64, BL=64, chunks NC=64.
//
// Precision scheme: B and SL are split-f16 (hi+lo); C, X, carry are f16-only.
// Per-operand f16 rounding contributes ~5e-4 relative; measured error floor
// (absmax 0.5) is exp-chain-dominated and identical for fp32 and split-f16 paths.
//
// k1: per-(b,c,h): cumsum(A) -> csw; local state (p x n) = X^T * (decay o B)
// k2: inter-chunk scan: carry[z] = exp(total[z-1])*(carry[z-1]+local[z-1]) (in-place)
// k3: per-(b,c,h): Y = ((C B^T) o L) X + exp(cs) o (C carry^T)
//
// MFMA = v_mfma_f32_16x16x16_f16 (classic layout):
//   A: row=lane&15, k=4*(lane>>4)+i ; B: col=lane&15 ; D: row=4*(lane>>4)+r, col=lane&15
// LDS tiles: [64 rows][128B], XOR-swizzle byte^=((row&7)<<4) on write & read.

#define NB 2
#define SQ 4096
#define NH 16
#define NC 64

typedef _Float16 h4 __attribute__((ext_vector_type(4)));
typedef float f4 __attribute__((ext_vector_type(4)));

#define MFMA(a, b, c) __builtin_amdgcn_mfma_f32_16x16x16f16((a), (b), (c), 0, 0, 0)

__device__ __forceinline__ int swzb(int row, int byte_in_row) {
  return (row << 7) + (byte_in_row ^ ((row & 7) << 4));
}
__device__ __forceinline__ h4 ldh4(const _Float16* buf, int row, int chunk8) {
  return *reinterpret_cast<const h4*>(reinterpret_cast<const char*>(buf) +
                                      swzb(row, chunk8 << 3));
}
__device__ __forceinline__ void sth4(_Float16* buf, int row, int chunk8, h4 v) {
  *reinterpret_cast<h4*>(reinterpret_cast<char*>(buf) + swzb(row, chunk8 << 3)) = v;
}
__device__ __forceinline__ void sth1(_Float16* buf, int row, int col, _Float16 v) {
  *reinterpret_cast<_Float16*>(reinterpret_cast<char*>(buf) + swzb(row, col << 1)) = v;
}
// split: x = hi + lo
__device__ __forceinline__ void cvt4(float x, float y, float z, float w, h4& hi, h4& lo) {
  hi.x = (_Float16)x; lo.x = (_Float16)(x - (float)hi.x);
  hi.y = (_Float16)y; lo.y = (_Float16)(y - (float)hi.y);
  hi.z = (_Float16)z; lo.z = (_Float16)(z - (float)hi.z);
  hi.w = (_Float16)w; lo.w = (_Float16)(w - (float)hi.w);
}
__device__ __forceinline__ h4 cvt4h(float x, float y, float z, float w) {
  h4 r; r.x = (_Float16)x; r.y = (_Float16)y; r.z = (_Float16)z; r.w = (_Float16)w;
  return r;
}

// ---------------------------------------------------------------- kernel 1
// LDS 24.8 KB -> 6 blocks/CU. X^T f16-only; (decay o B)^T split.
__global__ __launch_bounds__(256) void k1_state(
    const float* __restrict__ X, const float* __restrict__ A,
    const float* __restrict__ Bm, float* __restrict__ states,
    float* __restrict__ csw) {
  const int bid = blockIdx.x;
  const int h = bid & 15;
  const int c = (bid >> 4) & 63;
  const int b = bid >> 10;
  const int tid = threadIdx.x;

  __shared__ __align__(16) _Float16 Xthi[4096];              // X^T: [p][l] f16
  __shared__ __align__(16) _Float16 Bthi[4096], Btlo[4096];  // (d o B)^T: [n][l] split
  __shared__ float dss[64];

  if (tid < 64) {
    float v = A[(size_t)((b * SQ + c * 64 + tid) * NH) + h];
#pragma unroll
    for (int off = 1; off < 64; off <<= 1) {
      float u = __shfl_up(v, off, 64);
      if (tid >= off) v += u;
    }
    csw[(size_t)((b * NH + h) * NC + c) * 64 + tid] = v;
    float total = __shfl(v, 63, 64);
    dss[tid] = __expf(total - v);
  }
  __syncthreads();

  // transpose-stage X (f16) and decayed B (split)
  const int l = tid & 63, cb = tid >> 6;
  const float* xs = X + (size_t)(b * SQ + c * 64 + l) * 1024 + h * 64 + cb * 16;
  const float* bs = Bm + (size_t)(b * SQ + c * 64 + l) * 1024 + h * 64 + cb * 16;
  const float ds = dss[l];
#pragma unroll
  for (int i = 0; i < 4; ++i) {
    float4 xv = ((const float4*)xs)[i];
    float4 bv = ((const float4*)bs)[i];
    h4 hx = cvt4h(xv.x, xv.y, xv.z, xv.w);
    h4 hb, lb;
    cvt4(bv.x * ds, bv.y * ds, bv.z * ds, bv.w * ds, hb, lb);
    const int pr = cb * 16 + 4 * i;
    sth1(Xthi, pr + 0, l, hx.x);
    sth1(Xthi, pr + 1, l, hx.y);
    sth1(Xthi, pr + 2, l, hx.z);
    sth1(Xthi, pr + 3, l, hx.w);
    sth1(Bthi, pr + 0, l, hb.x); sth1(Btlo, pr + 0, l, lb.x);
    sth1(Bthi, pr + 1, l, hb.y); sth1(Btlo, pr + 1, l, lb.y);
    sth1(Bthi, pr + 2, l, hb.z); sth1(Btlo, pr + 2, l, lb.z);
    sth1(Bthi, pr + 3, l, hb.w); sth1(Btlo, pr + 3, l, lb.w);
  }
  __syncthreads();

  // states[p][n] = sum_l Xt[p][l] * Bt[n][l]
  const int w = tid >> 6, li = tid & 15, g = (tid & 63) >> 4;
  f4 acc[4] = {};
#pragma unroll
  for (int ks = 0; ks < 4; ++ks) {
    const int ca = 4 * ks + g;
    h4 ahi = ldh4(Xthi, 16 * w + li, ca);
#pragma unroll
    for (int ct = 0; ct < 4; ++ct) {
      h4 bhi = ldh4(Bthi, 16 * ct + li, ca);
      h4 blo = ldh4(Btlo, 16 * ct + li, ca);
      acc[ct] = MFMA(ahi, bhi, acc[ct]);
      acc[ct] = MFMA(ahi, blo, acc[ct]);
    }
  }
  float* sg = states + (size_t)bid * 4096;
#pragma unroll
  for (int r = 0; r < 4; ++r) {
    const int p = 16 * w + 4 * g + r;
#pragma unroll
    for (int ct = 0; ct < 4; ++ct) sg[p * 64 + 16 * ct + li] = acc[ct][r];
  }
}

// ---------------------------------------------------------------- kernel 2
// in-place scan over chunks; 8-deep load prefetch (latency-bound, 2 blocks/CU)
__global__ __launch_bounds__(256) void k2_scan(
    float* __restrict__ states, const float* __restrict__ csw) {
  const int tid = threadIdx.x;
  const int sl = blockIdx.x & 15;
  const int h = (blockIdx.x >> 4) & 15;
  const int b = blockIdx.x >> 8;

  __shared__ float et[64];
  if (tid < 64)
    et[tid] = __expf(csw[((size_t)(b * NH + h) * NC + tid) * 64 + 63]);
  __syncthreads();

  const int e = sl * 256 + tid;
  const size_t base = ((size_t)b * NC * NH + h) * 4096 + e;
  const size_t zs = (size_t)NH * 4096;

  float carry = 0.f;
  float pre[8];
#pragma unroll
  for (int j = 0; j < 8; ++j) pre[j] = states[base + (size_t)j * zs];
  for (int zb = 0; zb < 8; ++zb) {
    float cur[8];
#pragma unroll
    for (int j = 0; j < 8; ++j) cur[j] = pre[j];
    if (zb < 7) {
#pragma unroll
      for (int j = 0; j < 8; ++j)
        pre[j] = states[base + (size_t)(8 * zb + 8 + j) * zs];
    }
#pragma unroll
    for (int j = 0; j < 8; ++j) {
      const int z = 8 * zb + j;
      states[base + (size_t)z * zs] = carry;
      carry = et[z] * (carry + cur[j]);
    }
  }
}

// ---------------------------------------------------------------- kernel 3
// LDS 33 KB -> 4 blocks/CU. C/X/carry f16-only; B and SL split.
__global__ __launch_bounds__(256) void k3_y(
    const float* __restrict__ X, const float* __restrict__ Bm,
    const float* __restrict__ Cm, const float* __restrict__ states,
    const float* __restrict__ csw, float* __restrict__ Y) {
  const int bid = blockIdx.x;
  const int h = bid & 15;
  const int c = (bid >> 4) & 63;
  const int b = bid >> 10;
  const int tid = threadIdx.x;

  __shared__ __align__(16) _Float16 Chi[4096];               // C: [l][n] f16
  __shared__ __align__(16) _Float16 BShi[4096], BSlo[4096];  // B: [s][n] split -> SL: [l][s] split
  __shared__ __align__(16) _Float16 XVhi[4096];              // X^T: [p][s] f16 -> carry: [p][n] f16
  __shared__ float css[64];

  if (tid < 64)
    css[tid] = csw[((size_t)(b * NH + h) * NC + c) * 64 + tid];

  // prefetch carry (entering state) into registers; written to LDS after phase B
  const float* stg = states + (size_t)bid * 4096;
  const int r0 = tid >> 2, q0 = tid & 3;
  float4 cr[4];
#pragma unroll
  for (int i = 0; i < 4; ++i)
    cr[i] = ((const float4*)(stg + r0 * 64 + q0 * 16))[i];

  // direct staging: C (f16) and B (split), row-major rows r0
  {
    const float* cgp = Cm + (size_t)(b * SQ + c * 64 + r0) * 1024 + h * 64 + q0 * 16;
    const float* bgp = Bm + (size_t)(b * SQ + c * 64 + r0) * 1024 + h * 64 + q0 * 16;
#pragma unroll
    for (int i = 0; i < 4; ++i) {
      float4 cv = ((const float4*)cgp)[i];
      float4 bv = ((const float4*)bgp)[i];
      sth4(Chi, r0, q0 * 4 + i, cvt4h(cv.x, cv.y, cv.z, cv.w));
      h4 hb, lb;
      cvt4(bv.x, bv.y, bv.z, bv.w, hb, lb);
      sth4(BShi, r0, q0 * 4 + i, hb);
      sth4(BSlo, r0, q0 * 4 + i, lb);
    }
  }
  // transpose staging: X -> XVhi [p][s] (f16)
  {
    const int l = tid & 63, pb = tid >> 6;
    const float* xs = X + (size_t)(b * SQ + c * 64 + l) * 1024 + h * 64 + pb * 16;
#pragma unroll
    for (int i = 0; i < 4; ++i) {
      float4 xv = ((const float4*)xs)[i];
      h4 hx = cvt4h(xv.x, xv.y, xv.z, xv.w);
      const int pr = pb * 16 + 4 * i;
      sth1(XVhi, pr + 0, l, hx.x);
      sth1(XVhi, pr + 1, l, hx.y);
      sth1(XVhi, pr + 2, l, hx.z);
      sth1(XVhi, pr + 3, l, hx.w);
    }
  }
  __syncthreads();

  const int w = tid >> 6, li = tid & 15, g = (tid & 63) >> 4;

  // phase A: S[l][s] = sum_n C[l][n] * B[s][n]
  f4 accS[4] = {};
#pragma unroll
  for (int ks = 0; ks < 4; ++ks) {
    const int ca = 4 * ks + g;
    h4 ahi = ldh4(Chi, 16 * w + li, ca);
#pragma unroll
    for (int ct = 0; ct < 4; ++ct) {
      h4 bhi = ldh4(BShi, 16 * ct + li, ca);
      h4 blo = ldh4(BSlo, 16 * ct + li, ca);
      accS[ct] = MFMA(ahi, bhi, accS[ct]);
      accS[ct] = MFMA(ahi, blo, accS[ct]);
    }
  }
  __syncthreads();  // B-data reads done; BShi/BSlo become SL

  // SL[l][s] = (l>=s) ? S * exp(cs[l] - cs_excl[s]) : 0   (split store)
#pragma unroll
  for (int ct = 0; ct < 4; ++ct) {
    const int s = 16 * ct + li;
    const float cse = (s == 0) ? 0.f : css[s - 1];
#pragma unroll
    for (int r = 0; r < 4; ++r) {
      const int lrow = 16 * w + 4 * g + r;
      float slv = (lrow >= s) ? accS[ct][r] * __expf(css[lrow] - cse) : 0.f;
      _Float16 hv = (_Float16)slv;
      _Float16 lv = (_Float16)(slv - (float)hv);
      sth1(BShi, lrow, s, hv);
      sth1(BSlo, lrow, s, lv);
    }
  }
  __syncthreads();

  // phase B: Yd[l][p] = sum_s SL[l][s] * Xt[p][s]
  f4 accB[4] = {};
#pragma unroll
  for (int ks = 0; ks < 4; ++ks) {
    const int ca = 4 * ks + g;
    h4 ahi = ldh4(BShi, 16 * w + li, ca);
    h4 alo = ldh4(BSlo, 16 * w + li, ca);
#pragma unroll
    for (int ct = 0; ct < 4; ++ct) {
      h4 bhi = ldh4(XVhi, 16 * ct + li, ca);
      accB[ct] = MFMA(ahi, bhi, accB[ct]);
      accB[ct] = MFMA(alo, bhi, accB[ct]);
    }
  }
  __syncthreads();  // X reads done; XVhi becomes carry [p][n]

#pragma unroll
  for (int i = 0; i < 4; ++i)
    sth4(XVhi, r0, q0 * 4 + i, cvt4h(cr[i].x, cr[i].y, cr[i].z, cr[i].w));
  __syncthreads();

  // phase C: Yo[l][p] = sum_n C[l][n] * carry[p][n]
  f4 accC[4] = {};
#pragma unroll
  for (int ks = 0; ks < 4; ++ks) {
    const int ca = 4 * ks + g;
    h4 ahi = ldh4(Chi, 16 * w + li, ca);
#pragma unroll
    for (int ct = 0; ct < 4; ++ct) {
      h4 bhi = ldh4(XVhi, 16 * ct + li, ca);
      accC[ct] = MFMA(ahi, bhi, accC[ct]);
    }
  }

  // Y = Yd + exp(cs[l]) * Yo
  float* yg = Y + (size_t)(b * SQ + c * 64) * 1024 + h * 64;
#pragma unroll
  for (int r = 0; r < 4; ++r) {
    const int lrow = 16 * w + 4 * g + r;
    const float el = __expf(css[lrow]);
#pragma unroll
    for (int ct = 0; ct < 4; ++ct)
      yg[(size_t)lrow * 1024 + 16 * ct + li] = accB[ct][r] + el * accC[ct][r];
  }
}

// ---------------------------------------------------------------- launch
extern "C" void kernel_launch(void* const* d_in, const int* in_sizes, int n_in,
                              void* d_out, int out_size, void* d_ws, size_t ws_size,
                              hipStream_t stream) {
  (void)in_sizes; (void)n_in; (void)out_size; (void)ws_size;
  const float* X  = (const float*)d_in[0];
  const float* A  = (const float*)d_in[1];
  const float* Bm = (const float*)d_in[2];
  const float* Cm = (const float*)d_in[3];
  float* Y = (float*)d_out;

  float* states = (float*)d_ws;                             // 8388608 f32
  float* csw    = states + (size_t)NB * NC * NH * 64 * 64;  // 131072 f32

  k1_state<<<NB * NC * NH, 256, 0, stream>>>(X, A, Bm, states, csw);
  k2_scan<<<NB * NH * 16, 256, 0, stream>>>(states, csw);
  k3_y<<<NB * NC * NH, 256, 0, stream>>>(X, Bm, Cm, states, csw, Y);
}

// Round 5
// 168.722 us; speedup vs baseline: 1.2859x; 1.0377x over previous
//
#include <hip/hip_runtime.h>
#include <math.h>

// Mamba2 chunked SSD forward (inclusive segsum), fp32 in/out, mixed split-f16 MFMA.
// b=2, s=4096, h=16, p=n=64, BL=64, chunks NC=64.
//
// Pipeline:
//   k1: per-(b,c,h): cumsum(A) -> csw; local state (p x n) = X^T * (decay o B) -> f16 ws
//   k2: inter-chunk scan, alias-free: load all 64 -> reg scan -> store all 64 (f16)
//   k3: per-(b,c,h): Y = ((C B^T) o L) X + exp(cs) o (C carry^T); phases A & C merged,
//       3 barriers total (was 5) -- k3 is latency/serialization-bound, not ALU-bound.
//
// MFMA = v_mfma_f32_16x16x16_f16 (classic layout):
//   A: row=lane&15, k=4*(lane>>4)+i ; B: col=lane&15 ; D: row=4*(lane>>4)+r, col=lane&15
// LDS tiles: [64 rows][128B], XOR-swizzle byte^=((row&7)<<4) on write & read.

#define NB 2
#define SQ 4096
#define NH 16
#define NC 64

typedef _Float16 h4 __attribute__((ext_vector_type(4)));
typedef float f4 __attribute__((ext_vector_type(4)));

#define MFMA(a, b, c) __builtin_amdgcn_mfma_f32_16x16x16f16((a), (b), (c), 0, 0, 0)

__device__ __forceinline__ int swzb(int row, int byte_in_row) {
  return (row << 7) + (byte_in_row ^ ((row & 7) << 4));
}
__device__ __forceinline__ h4 ldh4(const _Float16* buf, int row, int chunk8) {
  return *reinterpret_cast<const h4*>(reinterpret_cast<const char*>(buf) +
                                      swzb(row, chunk8 << 3));
}
__device__ __forceinline__ void sth4(_Float16* buf, int row, int chunk8, h4 v) {
  *reinterpret_cast<h4*>(reinterpret_cast<char*>(buf) + swzb(row, chunk8 << 3)) = v;
}
__device__ __forceinline__ void sth1(_Float16* buf, int row, int col, _Float16 v) {
  *reinterpret_cast<_Float16*>(reinterpret_cast<char*>(buf) + swzb(row, col << 1)) = v;
}
// split: x = hi + lo
__device__ __forceinline__ void cvt4(float x, float y, float z, float w, h4& hi, h4& lo) {
  hi.x = (_Float16)x; lo.x = (_Float16)(x - (float)hi.x);
  hi.y = (_Float16)y; lo.y = (_Float16)(y - (float)hi.y);
  hi.z = (_Float16)z; lo.z = (_Float16)(z - (float)hi.z);
  hi.w = (_Float16)w; lo.w = (_Float16)(w - (float)hi.w);
}
__device__ __forceinline__ h4 cvt4h(float x, float y, float z, float w) {
  h4 r; r.x = (_Float16)x; r.y = (_Float16)y; r.z = (_Float16)z; r.w = (_Float16)w;
  return r;
}

// ---------------------------------------------------------------- kernel 1
// LDS 24.8 KB. X^T f16-only; (decay o B)^T split. States written as f16.
__global__ __launch_bounds__(256) void k1_state(
    const float* __restrict__ X, const float* __restrict__ A,
    const float* __restrict__ Bm, _Float16* __restrict__ states,
    float* __restrict__ csw) {
  const int bid = blockIdx.x;
  const int h = bid & 15;
  const int c = (bid >> 4) & 63;
  const int b = bid >> 10;
  const int tid = threadIdx.x;

  __shared__ __align__(16) _Float16 Xthi[4096];              // X^T: [p][l] f16
  __shared__ __align__(16) _Float16 Bthi[4096], Btlo[4096];  // (d o B)^T: [n][l] split
  __shared__ float dss[64];

  if (tid < 64) {
    float v = A[(size_t)((b * SQ + c * 64 + tid) * NH) + h];
#pragma unroll
    for (int off = 1; off < 64; off <<= 1) {
      float u = __shfl_up(v, off, 64);
      if (tid >= off) v += u;
    }
    csw[(size_t)((b * NH + h) * NC + c) * 64 + tid] = v;
    float total = __shfl(v, 63, 64);
    dss[tid] = __expf(total - v);
  }
  __syncthreads();

  // transpose-stage X (f16) and decayed B (split)
  const int l = tid & 63, cb = tid >> 6;
  const float* xs = X + (size_t)(b * SQ + c * 64 + l) * 1024 + h * 64 + cb * 16;
  const float* bs = Bm + (size_t)(b * SQ + c * 64 + l) * 1024 + h * 64 + cb * 16;
  const float ds = dss[l];
#pragma unroll
  for (int i = 0; i < 4; ++i) {
    float4 xv = ((const float4*)xs)[i];
    float4 bv = ((const float4*)bs)[i];
    h4 hx = cvt4h(xv.x, xv.y, xv.z, xv.w);
    h4 hb, lb;
    cvt4(bv.x * ds, bv.y * ds, bv.z * ds, bv.w * ds, hb, lb);
    const int pr = cb * 16 + 4 * i;
    sth1(Xthi, pr + 0, l, hx.x);
    sth1(Xthi, pr + 1, l, hx.y);
    sth1(Xthi, pr + 2, l, hx.z);
    sth1(Xthi, pr + 3, l, hx.w);
    sth1(Bthi, pr + 0, l, hb.x); sth1(Btlo, pr + 0, l, lb.x);
    sth1(Bthi, pr + 1, l, hb.y); sth1(Btlo, pr + 1, l, lb.y);
    sth1(Bthi, pr + 2, l, hb.z); sth1(Btlo, pr + 2, l, lb.z);
    sth1(Bthi, pr + 3, l, hb.w); sth1(Btlo, pr + 3, l, lb.w);
  }
  __syncthreads();

  // states[p][n] = sum_l Xt[p][l] * Bt[n][l]
  const int w = tid >> 6, li = tid & 15, g = (tid & 63) >> 4;
  f4 acc[4] = {};
#pragma unroll
  for (int ks = 0; ks < 4; ++ks) {
    const int ca = 4 * ks + g;
    h4 ahi = ldh4(Xthi, 16 * w + li, ca);
#pragma unroll
    for (int ct = 0; ct < 4; ++ct) {
      h4 bhi = ldh4(Bthi, 16 * ct + li, ca);
      h4 blo = ldh4(Btlo, 16 * ct + li, ca);
      acc[ct] = MFMA(ahi, bhi, acc[ct]);
      acc[ct] = MFMA(ahi, blo, acc[ct]);
    }
  }
  _Float16* sg = states + (size_t)bid * 4096;
#pragma unroll
  for (int r = 0; r < 4; ++r) {
    const int p = 16 * w + 4 * g + r;
#pragma unroll
    for (int ct = 0; ct < 4; ++ct)
      sg[p * 64 + 16 * ct + li] = (_Float16)acc[ct][r];
  }
}

// ---------------------------------------------------------------- kernel 2
// alias-free in-place scan: load ALL 64 chunk values to regs, scan, store all.
__global__ __launch_bounds__(256) void k2_scan(
    _Float16* __restrict__ states, const float* __restrict__ csw) {
  const int tid = threadIdx.x;
  const int sl = blockIdx.x & 15;
  const int h = (blockIdx.x >> 4) & 15;
  const int b = blockIdx.x >> 8;

  __shared__ float et[64];
  if (tid < 64)
    et[tid] = __expf(csw[((size_t)(b * NH + h) * NC + tid) * 64 + 63]);
  __syncthreads();

  const int e = sl * 256 + tid;
  const size_t base = ((size_t)b * NC * NH + h) * 4096 + e;
  const size_t zs = (size_t)NH * 4096;

  float v[64];
#pragma unroll
  for (int z = 0; z < 64; ++z) v[z] = (float)states[base + (size_t)z * zs];

  float carry = 0.f;
#pragma unroll
  for (int z = 0; z < 64; ++z) {
    const float nxt = et[z] * (carry + v[z]);
    v[z] = carry;       // entering state of chunk z
    carry = nxt;
  }

#pragma unroll
  for (int z = 0; z < 64; ++z) states[base + (size_t)z * zs] = (_Float16)v[z];
}

// ---------------------------------------------------------------- kernel 3
// LDS 40.25 KB. Phases A (S=C B^T) and C (Yo=C carry^T) merged; 3 barriers.
__global__ __launch_bounds__(256) void k3_y(
    const float* __restrict__ X, const float* __restrict__ Bm,
    const float* __restrict__ Cm, const _Float16* __restrict__ states,
    const float* __restrict__ csw, float* __restrict__ Y) {
  const int bid = blockIdx.x;
  const int h = bid & 15;
  const int c = (bid >> 4) & 63;
  const int b = bid >> 10;
  const int tid = threadIdx.x;

  __shared__ __align__(16) _Float16 Chi[4096];               // C: [l][n] f16
  __shared__ __align__(16) _Float16 BShi[4096], BSlo[4096];  // B: [s][n] split -> SL: [l][s] split
  __shared__ __align__(16) _Float16 XVhi[4096];              // X^T: [p][s] f16
  __shared__ __align__(16) _Float16 Ghi[4096];               // carry: [p][n] f16
  __shared__ float css[64];

  if (tid < 64)
    css[tid] = csw[((size_t)(b * NH + h) * NC + c) * 64 + tid];

  const int r0 = tid >> 2, q0 = tid & 3;
  // direct staging: C (f16), B (split), carry (f16 from ws), row-major rows r0
  {
    const float* cgp = Cm + (size_t)(b * SQ + c * 64 + r0) * 1024 + h * 64 + q0 * 16;
    const float* bgp = Bm + (size_t)(b * SQ + c * 64 + r0) * 1024 + h * 64 + q0 * 16;
    const _Float16* stg = states + (size_t)bid * 4096 + r0 * 64 + q0 * 16;
#pragma unroll
    for (int i = 0; i < 4; ++i) {
      float4 cv = ((const float4*)cgp)[i];
      float4 bv = ((const float4*)bgp)[i];
      h4 gv = ((const h4*)stg)[i];
      sth4(Chi, r0, q0 * 4 + i, cvt4h(cv.x, cv.y, cv.z, cv.w));
      h4 hb, lb;
      cvt4(bv.x, bv.y, bv.z, bv.w, hb, lb);
      sth4(BShi, r0, q0 * 4 + i, hb);
      sth4(BSlo, r0, q0 * 4 + i, lb);
      sth4(Ghi, r0, q0 * 4 + i, gv);
    }
  }
  // transpose staging: X -> XVhi [p][s] (f16)
  {
    const int l = tid & 63, pb = tid >> 6;
    const float* xs = X + (size_t)(b * SQ + c * 64 + l) * 1024 + h * 64 + pb * 16;
#pragma unroll
    for (int i = 0; i < 4; ++i) {
      float4 xv = ((const float4*)xs)[i];
      h4 hx = cvt4h(xv.x, xv.y, xv.z, xv.w);
      const int pr = pb * 16 + 4 * i;
      sth1(XVhi, pr + 0, l, hx.x);
      sth1(XVhi, pr + 1, l, hx.y);
      sth1(XVhi, pr + 2, l, hx.z);
      sth1(XVhi, pr + 3, l, hx.w);
    }
  }
  __syncthreads();  // barrier 1

  const int w = tid >> 6, li = tid & 15, g = (tid & 63) >> 4;

  // phase A+C merged: S[l][s] = sum_n C[l][n]*B[s][n]; Yo[l][p] = sum_n C[l][n]*carry[p][n]
  f4 accS[4] = {};
  f4 accC[4] = {};
#pragma unroll
  for (int ks = 0; ks < 4; ++ks) {
    const int ca = 4 * ks + g;
    h4 ahi = ldh4(Chi, 16 * w + li, ca);
#pragma unroll
    for (int ct = 0; ct < 4; ++ct) {
      h4 bhi = ldh4(BShi, 16 * ct + li, ca);
      h4 blo = ldh4(BSlo, 16 * ct + li, ca);
      h4 ghi = ldh4(Ghi, 16 * ct + li, ca);
      accS[ct] = MFMA(ahi, bhi, accS[ct]);
      accS[ct] = MFMA(ahi, blo, accS[ct]);
      accC[ct] = MFMA(ahi, ghi, accC[ct]);
    }
  }
  __syncthreads();  // barrier 2: B-data reads done; BShi/BSlo become SL

  // SL[l][s] = (l>=s) ? S * exp(cs[l] - cs_excl[s]) : 0   (split store)
#pragma unroll
  for (int ct = 0; ct < 4; ++ct) {
    const int s = 16 * ct + li;
    const float cse = (s == 0) ? 0.f : css[s - 1];
#pragma unroll
    for (int r = 0; r < 4; ++r) {
      const int lrow = 16 * w + 4 * g + r;
      float slv = (lrow >= s) ? accS[ct][r] * __expf(css[lrow] - cse) : 0.f;
      _Float16 hv = (_Float16)slv;
      _Float16 lv = (_Float16)(slv - (float)hv);
      sth1(BShi, lrow, s, hv);
      sth1(BSlo, lrow, s, lv);
    }
  }
  __syncthreads();  // barrier 3

  // phase B: Yd[l][p] = sum_s SL[l][s] * Xt[p][s]
  f4 accB[4] = {};
#pragma unroll
  for (int ks = 0; ks < 4; ++ks) {
    const int ca = 4 * ks + g;
    h4 ahi = ldh4(BShi, 16 * w + li, ca);
    h4 alo = ldh4(BSlo, 16 * w + li, ca);
#pragma unroll
    for (int ct = 0; ct < 4; ++ct) {
      h4 bhi = ldh4(XVhi, 16 * ct + li, ca);
      accB[ct] = MFMA(ahi, bhi, accB[ct]);
      accB[ct] = MFMA(alo, bhi, accB[ct]);
    }
  }

  // Y = Yd + exp(cs[l]) * Yo
  float* yg = Y + (size_t)(b * SQ + c * 64) * 1024 + h * 64;
#pragma unroll
  for (int r = 0; r < 4; ++r) {
    const int lrow = 16 * w + 4 * g + r;
    const float el = __expf(css[lrow]);
#pragma unroll
    for (int ct = 0; ct < 4; ++ct)
      yg[(size_t)lrow * 1024 + 16 * ct + li] = accB[ct][r] + el * accC[ct][r];
  }
}

// ---------------------------------------------------------------- launch
extern "C" void kernel_launch(void* const* d_in, const int* in_sizes, int n_in,
                              void* d_out, int out_size, void* d_ws, size_t ws_size,
                              hipStream_t stream) {
  (void)in_sizes; (void)n_in; (void)out_size; (void)ws_size;
  const float* X  = (const float*)d_in[0];
  const float* A  = (const float*)d_in[1];
  const float* Bm = (const float*)d_in[2];
  const float* Cm = (const float*)d_in[3];
  float* Y = (float*)d_out;

  _Float16* states = (_Float16*)d_ws;  // 8388608 f16 = 16.8 MB
  float* csw = (float*)((char*)d_ws +
                        (size_t)NB * NC * NH * 64 * 64 * sizeof(_Float16));

  k1_state<<<NB * NC * NH, 256, 0, stream>>>(X, A, Bm, states, csw);
  k2_scan<<<NB * NH * 16, 256, 0, stream>>>(states, csw);
  k3_y<<<NB * NC * NH, 256, 0, stream>>>(X, Bm, Cm, states, csw, Y);
}

// Round 6
// 166.134 us; speedup vs baseline: 1.3060x; 1.0156x over previous
//
#include <hip/hip_runtime.h>
#include <math.h>

// Mamba2 chunked SSD forward (inclusive segsum), fp32 in/out, mixed split-f16 MFMA.
// b=2, s=4096, h=16, p=n=64, BL=64, chunks NC=64.
//
// Pipeline:
//   k1: per-(b,c,h): cumsum(A) -> csw; local state (p x n) = X^T * (decay o B) -> f16 ws
//   k2: inter-chunk scan, alias-free: load all 64 -> reg scan -> store all 64 (f16)
//   k3: per-(b,c,h): Y = ((C B^T) o L) X + exp(cs) o (C carry^T); phases A & C merged.
//
// Round-6 change: k1/k3 use 512-thread blocks (8 waves, 2 output tiles each:
// row-block w&3, col-half w>>2) -> 24 waves/CU resident at 3 blocks/CU (was 12),
// halving per-block critical path. k3 is latency-bound (r4: MFMA count -44% gave
// +0%); occupancy is the lever, not instruction count.
//
// MFMA = v_mfma_f32_16x16x16_f16 (classic layout):
//   A: row=lane&15, k=4*(lane>>4)+i ; B: col=lane&15 ; D: row=4*(lane>>4)+r, col=lane&15
// LDS tiles: [64 rows][128B], XOR-swizzle byte^=((row&7)<<4) on write & read.

#define NB 2
#define SQ 4096
#define NH 16
#define NC 64

typedef _Float16 h4 __attribute__((ext_vector_type(4)));
typedef float f4 __attribute__((ext_vector_type(4)));

#define MFMA(a, b, c) __builtin_amdgcn_mfma_f32_16x16x16f16((a), (b), (c), 0, 0, 0)

__device__ __forceinline__ int swzb(int row, int byte_in_row) {
  return (row << 7) + (byte_in_row ^ ((row & 7) << 4));
}
__device__ __forceinline__ h4 ldh4(const _Float16* buf, int row, int chunk8) {
  return *reinterpret_cast<const h4*>(reinterpret_cast<const char*>(buf) +
                                      swzb(row, chunk8 << 3));
}
__device__ __forceinline__ void sth4(_Float16* buf, int row, int chunk8, h4 v) {
  *reinterpret_cast<h4*>(reinterpret_cast<char*>(buf) + swzb(row, chunk8 << 3)) = v;
}
__device__ __forceinline__ void sth1(_Float16* buf, int row, int col, _Float16 v) {
  *reinterpret_cast<_Float16*>(reinterpret_cast<char*>(buf) + swzb(row, col << 1)) = v;
}
// split: x = hi + lo
__device__ __forceinline__ void cvt4(float x, float y, float z, float w, h4& hi, h4& lo) {
  hi.x = (_Float16)x; lo.x = (_Float16)(x - (float)hi.x);
  hi.y = (_Float16)y; lo.y = (_Float16)(y - (float)hi.y);
  hi.z = (_Float16)z; lo.z = (_Float16)(z - (float)hi.z);
  hi.w = (_Float16)w; lo.w = (_Float16)(w - (float)hi.w);
}
__device__ __forceinline__ h4 cvt4h(float x, float y, float z, float w) {
  h4 r; r.x = (_Float16)x; r.y = (_Float16)y; r.z = (_Float16)z; r.w = (_Float16)w;
  return r;
}

// ---------------------------------------------------------------- kernel 1
// 512 threads, LDS 24.8 KB. X^T f16-only; (decay o B)^T split. States f16.
__global__ __launch_bounds__(512) void k1_state(
    const float* __restrict__ X, const float* __restrict__ A,
    const float* __restrict__ Bm, _Float16* __restrict__ states,
    float* __restrict__ csw) {
  const int bid = blockIdx.x;
  const int h = bid & 15;
  const int c = (bid >> 4) & 63;
  const int b = bid >> 10;
  const int tid = threadIdx.x;

  __shared__ __align__(16) _Float16 Xthi[4096];              // X^T: [p][l] f16
  __shared__ __align__(16) _Float16 Bthi[4096], Btlo[4096];  // (d o B)^T: [n][l] split
  __shared__ float dss[64];

  if (tid < 64) {
    float v = A[(size_t)((b * SQ + c * 64 + tid) * NH) + h];
#pragma unroll
    for (int off = 1; off < 64; off <<= 1) {
      float u = __shfl_up(v, off, 64);
      if (tid >= off) v += u;
    }
    csw[(size_t)((b * NH + h) * NC + c) * 64 + tid] = v;
    float total = __shfl(v, 63, 64);
    dss[tid] = __expf(total - v);
  }
  __syncthreads();

  // transpose-stage X (f16) and decayed B (split): 8 threads/row, 8 cols each
  const int l = tid & 63, cb = tid >> 6;  // cb in 0..7
  const float* xs = X + (size_t)(b * SQ + c * 64 + l) * 1024 + h * 64 + cb * 8;
  const float* bs = Bm + (size_t)(b * SQ + c * 64 + l) * 1024 + h * 64 + cb * 8;
  const float ds = dss[l];
#pragma unroll
  for (int i = 0; i < 2; ++i) {
    float4 xv = ((const float4*)xs)[i];
    float4 bv = ((const float4*)bs)[i];
    h4 hx = cvt4h(xv.x, xv.y, xv.z, xv.w);
    h4 hb, lb;
    cvt4(bv.x * ds, bv.y * ds, bv.z * ds, bv.w * ds, hb, lb);
    const int pr = cb * 8 + 4 * i;
    sth1(Xthi, pr + 0, l, hx.x);
    sth1(Xthi, pr + 1, l, hx.y);
    sth1(Xthi, pr + 2, l, hx.z);
    sth1(Xthi, pr + 3, l, hx.w);
    sth1(Bthi, pr + 0, l, hb.x); sth1(Btlo, pr + 0, l, lb.x);
    sth1(Bthi, pr + 1, l, hb.y); sth1(Btlo, pr + 1, l, lb.y);
    sth1(Bthi, pr + 2, l, hb.z); sth1(Btlo, pr + 2, l, lb.z);
    sth1(Bthi, pr + 3, l, hb.w); sth1(Btlo, pr + 3, l, lb.w);
  }
  __syncthreads();

  // states[p][n] = sum_l Xt[p][l] * Bt[n][l]
  // wave w: p row-block a=w&3, n col-half ch=w>>2 (2 tiles)
  const int w = tid >> 6, li = tid & 15, g = (tid & 63) >> 4;
  const int a = w & 3, ch = w >> 2;
  f4 acc[2] = {};
#pragma unroll
  for (int ks = 0; ks < 4; ++ks) {
    const int ca = 4 * ks + g;
    h4 ahi = ldh4(Xthi, 16 * a + li, ca);
#pragma unroll
    for (int j = 0; j < 2; ++j) {
      const int ct = 2 * ch + j;
      h4 bhi = ldh4(Bthi, 16 * ct + li, ca);
      h4 blo = ldh4(Btlo, 16 * ct + li, ca);
      acc[j] = MFMA(ahi, bhi, acc[j]);
      acc[j] = MFMA(ahi, blo, acc[j]);
    }
  }
  _Float16* sg = states + (size_t)bid * 4096;
#pragma unroll
  for (int r = 0; r < 4; ++r) {
    const int p = 16 * a + 4 * g + r;
#pragma unroll
    for (int j = 0; j < 2; ++j)
      sg[p * 64 + 16 * (2 * ch + j) + li] = (_Float16)acc[j][r];
  }
}

// ---------------------------------------------------------------- kernel 2
// alias-free in-place scan: load ALL 64 chunk values to regs, scan, store all.
__global__ __launch_bounds__(256) void k2_scan(
    _Float16* __restrict__ states, const float* __restrict__ csw) {
  const int tid = threadIdx.x;
  const int sl = blockIdx.x & 15;
  const int h = (blockIdx.x >> 4) & 15;
  const int b = blockIdx.x >> 8;

  __shared__ float et[64];
  if (tid < 64)
    et[tid] = __expf(csw[((size_t)(b * NH + h) * NC + tid) * 64 + 63]);
  __syncthreads();

  const int e = sl * 256 + tid;
  const size_t base = ((size_t)b * NC * NH + h) * 4096 + e;
  const size_t zs = (size_t)NH * 4096;

  float v[64];
#pragma unroll
  for (int z = 0; z < 64; ++z) v[z] = (float)states[base + (size_t)z * zs];

  float carry = 0.f;
#pragma unroll
  for (int z = 0; z < 64; ++z) {
    const float nxt = et[z] * (carry + v[z]);
    v[z] = carry;  // entering state of chunk z
    carry = nxt;
  }

#pragma unroll
  for (int z = 0; z < 64; ++z) states[base + (size_t)z * zs] = (_Float16)v[z];
}

// ---------------------------------------------------------------- kernel 3
// 512 threads, LDS 40.25 KB. Phases A (S=C B^T) and C (Yo=C carry^T) merged.
__global__ __launch_bounds__(512) void k3_y(
    const float* __restrict__ X, const float* __restrict__ Bm,
    const float* __restrict__ Cm, const _Float16* __restrict__ states,
    const float* __restrict__ csw, float* __restrict__ Y) {
  const int bid = blockIdx.x;
  const int h = bid & 15;
  const int c = (bid >> 4) & 63;
  const int b = bid >> 10;
  const int tid = threadIdx.x;

  __shared__ __align__(16) _Float16 Chi[4096];               // C: [l][n] f16
  __shared__ __align__(16) _Float16 BShi[4096], BSlo[4096];  // B: [s][n] split -> SL: [l][s] split
  __shared__ __align__(16) _Float16 XVhi[4096];              // X^T: [p][s] f16
  __shared__ __align__(16) _Float16 Ghi[4096];               // carry: [p][n] f16
  __shared__ float css[64];

  if (tid < 64)
    css[tid] = csw[((size_t)(b * NH + h) * NC + c) * 64 + tid];

  // direct staging: C (f16), B (split), carry (f16 from ws): 8 threads/row
  const int r0 = tid >> 3, q0 = tid & 7;
  {
    const float* cgp = Cm + (size_t)(b * SQ + c * 64 + r0) * 1024 + h * 64 + q0 * 8;
    const float* bgp = Bm + (size_t)(b * SQ + c * 64 + r0) * 1024 + h * 64 + q0 * 8;
    const _Float16* stg = states + (size_t)bid * 4096 + r0 * 64 + q0 * 8;
#pragma unroll
    for (int i = 0; i < 2; ++i) {
      float4 cv = ((const float4*)cgp)[i];
      float4 bv = ((const float4*)bgp)[i];
      h4 gv = ((const h4*)stg)[i];
      sth4(Chi, r0, 2 * q0 + i, cvt4h(cv.x, cv.y, cv.z, cv.w));
      h4 hb, lb;
      cvt4(bv.x, bv.y, bv.z, bv.w, hb, lb);
      sth4(BShi, r0, 2 * q0 + i, hb);
      sth4(BSlo, r0, 2 * q0 + i, lb);
      sth4(Ghi, r0, 2 * q0 + i, gv);
    }
  }
  // transpose staging: X -> XVhi [p][s] (f16): 8 p-blocks of 8
  {
    const int l = tid & 63, pb = tid >> 6;
    const float* xs = X + (size_t)(b * SQ + c * 64 + l) * 1024 + h * 64 + pb * 8;
#pragma unroll
    for (int i = 0; i < 2; ++i) {
      float4 xv = ((const float4*)xs)[i];
      h4 hx = cvt4h(xv.x, xv.y, xv.z, xv.w);
      const int pr = pb * 8 + 4 * i;
      sth1(XVhi, pr + 0, l, hx.x);
      sth1(XVhi, pr + 1, l, hx.y);
      sth1(XVhi, pr + 2, l, hx.z);
      sth1(XVhi, pr + 3, l, hx.w);
    }
  }
  __syncthreads();  // barrier 1

  // wave w: row-block a=w&3 (l-rows 16a..16a+15), col-half ch=w>>2 (2 tiles)
  const int w = tid >> 6, li = tid & 15, g = (tid & 63) >> 4;
  const int a = w & 3, ch = w >> 2;

  // phase A+C merged: S[l][s]=sum_n C[l][n]B[s][n]; Yo[l][p]=sum_n C[l][n]carry[p][n]
  f4 accS[2] = {};
  f4 accC[2] = {};
#pragma unroll
  for (int ks = 0; ks < 4; ++ks) {
    const int ca = 4 * ks + g;
    h4 ahi = ldh4(Chi, 16 * a + li, ca);
#pragma unroll
    for (int j = 0; j < 2; ++j) {
      const int ct = 2 * ch + j;
      h4 bhi = ldh4(BShi, 16 * ct + li, ca);
      h4 blo = ldh4(BSlo, 16 * ct + li, ca);
      h4 ghi = ldh4(Ghi, 16 * ct + li, ca);
      accS[j] = MFMA(ahi, bhi, accS[j]);
      accS[j] = MFMA(ahi, blo, accS[j]);
      accC[j] = MFMA(ahi, ghi, accC[j]);
    }
  }
  __syncthreads();  // barrier 2: B-data reads done; BShi/BSlo become SL

  // SL[l][s] = (l>=s) ? S * exp(cs[l] - cs_excl[s]) : 0   (split store)
#pragma unroll
  for (int j = 0; j < 2; ++j) {
    const int s = 16 * (2 * ch + j) + li;
    const float cse = (s == 0) ? 0.f : css[s - 1];
#pragma unroll
    for (int r = 0; r < 4; ++r) {
      const int lrow = 16 * a + 4 * g + r;
      float slv = (lrow >= s) ? accS[j][r] * __expf(css[lrow] - cse) : 0.f;
      _Float16 hv = (_Float16)slv;
      _Float16 lv = (_Float16)(slv - (float)hv);
      sth1(BShi, lrow, s, hv);
      sth1(BSlo, lrow, s, lv);
    }
  }
  __syncthreads();  // barrier 3

  // phase B: Yd[l][p] = sum_s SL[l][s] * Xt[p][s]
  f4 accB[2] = {};
#pragma unroll
  for (int ks = 0; ks < 4; ++ks) {
    const int ca = 4 * ks + g;
    h4 ahi = ldh4(BShi, 16 * a + li, ca);
    h4 alo = ldh4(BSlo, 16 * a + li, ca);
#pragma unroll
    for (int j = 0; j < 2; ++j) {
      h4 bhi = ldh4(XVhi, 16 * (2 * ch + j) + li, ca);
      accB[j] = MFMA(ahi, bhi, accB[j]);
      accB[j] = MFMA(alo, bhi, accB[j]);
    }
  }

  // Y = Yd + exp(cs[l]) * Yo
  float* yg = Y + (size_t)(b * SQ + c * 64) * 1024 + h * 64;
#pragma unroll
  for (int r = 0; r < 4; ++r) {
    const int lrow = 16 * a + 4 * g + r;
    const float el = __expf(css[lrow]);
#pragma unroll
    for (int j = 0; j < 2; ++j)
      yg[(size_t)lrow * 1024 + 16 * (2 * ch + j) + li] = accB[j][r] + el * accC[j][r];
  }
}

// ---------------------------------------------------------------- launch
extern "C" void kernel_launch(void* const* d_in, const int* in_sizes, int n_in,
                              void* d_out, int out_size, void* d_ws, size_t ws_size,
                              hipStream_t stream) {
  (void)in_sizes; (void)n_in; (void)out_size; (void)ws_size;
  const float* X  = (const float*)d_in[0];
  const float* A  = (const float*)d_in[1];
  const float* Bm = (const float*)d_in[2];
  const float* Cm = (const float*)d_in[3];
  float* Y = (float*)d_out;

  _Float16* states = (_Float16*)d_ws;  // 8388608 f16 = 16.8 MB
  float* csw = (float*)((char*)d_ws +
                        (size_t)NB * NC * NH * 64 * 64 * sizeof(_Float16));

  k1_state<<<NB * NC * NH, 512, 0, stream>>>(X, A, Bm, states, csw);
  k2_scan<<<NB * NH * 16, 256, 0, stream>>>(states, csw);
  k3_y<<<NB * NC * NH, 512, 0, stream>>>(X, Bm, Cm, states, csw, Y);
}